// Round 8
// baseline (330.246 us; speedup 1.0000x reference)
//
#include <hip/hip_runtime.h>

// imgs (8,3,1024,1024) fp32, z (1e6,2) fp32 -> out (8,2) fp32.
// R8: atomic-free gather form of the linear reformulation.
//   gc0(point) = Dy[yg][xg] + u*M[yg][xg],  gc1 = Dx[yg][xg] + v*M[yg][xg]
// with S_b = sum_c imgs[b,c], Dy=S(y+1,x)-S(y,x), Dx=S(y,x+1)-S(y,x),
// M = S(y+1,x+1)-S(y,x+1)-S(y+1,x)+S(y,x)  (algebra verified vs reference:
// fx=-u, fy=-v, d=-M, gc0=d*fx+a1=u*M+Dy, gc1=d*fy+a3=v*M+Dx).
// Precompute T[pixel][b] = float4(Dy,Dx,M,M), pixel-major: one point reads ONE
// aligned 128 B line covering all 8 batches. 1M random line READS replace R7's
// 1M random-line atomic RMWs (~20 G/s rate limit); no zeroing pass needed.

#define NYX 1024
#define NPIX (NYX * NYX)
#define BATCH 8
#define CH 3
#define GB 1024                     // gather blocks
#define PART_OFF ((size_t)NPIX * BATCH * 16)   // 128 MB of T, then partials

__global__ __launch_bounds__(256) void precompute_kernel(
    const float* __restrict__ imgs, float4* __restrict__ T4)
{
    int y   = blockIdx.x;                 // one row per block
    int yp1 = min(y + 1, NYX - 1);        // y=1023 rows produce garbage, never read
    int x0  = threadIdx.x * 4;
    int x4  = min(x0 + 4, NYX - 4);       // 5th-element column (garbage at row end, unread)

#pragma unroll
    for (int b = 0; b < BATCH; ++b) {
        float4 ca = make_float4(0.f, 0.f, 0.f, 0.f);   // S_b row y   [x0..x0+3]
        float4 na = make_float4(0.f, 0.f, 0.f, 0.f);   // S_b row y+1 [x0..x0+3]
        float cb = 0.f, nb = 0.f;                      // S_b at x0+4
#pragma unroll
        for (int c = 0; c < CH; ++c) {
            const float* pl = imgs + (size_t)(b * CH + c) * NPIX;
            const float4* r0 = (const float4*)(pl + (size_t)y   * NYX);
            const float4* r1 = (const float4*)(pl + (size_t)yp1 * NYX);
            float4 v0 = r0[threadIdx.x];
            float4 v1 = r1[threadIdx.x];
            ca.x += v0.x; ca.y += v0.y; ca.z += v0.z; ca.w += v0.w;
            na.x += v1.x; na.y += v1.y; na.z += v1.z; na.w += v1.w;
            cb += pl[(size_t)y   * NYX + x4];
            nb += pl[(size_t)yp1 * NYX + x4];
        }
        float c5[5] = {ca.x, ca.y, ca.z, ca.w, cb};
        float n5[5] = {na.x, na.y, na.z, na.w, nb};
        size_t base = ((size_t)y * NYX + x0) * BATCH + b;
#pragma unroll
        for (int i = 0; i < 4; ++i) {
            float Dy = n5[i] - c5[i];
            float Dx = c5[i + 1] - c5[i];
            float M  = (n5[i + 1] - c5[i + 1]) - Dy;
            T4[base + (size_t)i * BATCH] = make_float4(Dy, Dx, M, M);
        }
    }
}

__global__ __launch_bounds__(256) void gather_kernel(
    const float* __restrict__ z, const float4* __restrict__ T4,
    float* __restrict__ partials, int npts)
{
    float acc0[BATCH];
    float acc1[BATCH];
#pragma unroll
    for (int b = 0; b < BATCH; ++b) { acc0[b] = 0.0f; acc1[b] = 0.0f; }

    int stride = gridDim.x * blockDim.x;
    for (int p = blockIdx.x * blockDim.x + threadIdx.x; p < npts; p += stride) {
        float2 zz = ((const float2*)z)[p];
        float x0y = zz.x * (float)(NYX - 1);
        float x0x = zz.y * (float)(NYX - 1);
        bool oob = (x0y < 0.0f) || (x0y > (float)(NYX - 1)) ||
                   (x0x < 0.0f) || (x0x > (float)(NYX - 1));
        if (oob) continue;
        int yg = min((int)floorf(x0y), NYX - 2);
        int xg = min((int)floorf(x0x), NYX - 2);
        float u = x0x - (float)xg;   // [0,1)
        float v = x0y - (float)yg;
        const float4* t = T4 + ((size_t)yg * NYX + xg) * BATCH;  // one 128 B line
#pragma unroll
        for (int b = 0; b < BATCH; ++b) {
            float4 w = t[b];                 // (Dy, Dx, M, M)
            acc0[b] += fmaf(u, w.z, w.x);
            acc1[b] += fmaf(v, w.w, w.y);
        }
    }

#pragma unroll
    for (int b = 0; b < BATCH; ++b) {
#pragma unroll
        for (int off = 32; off > 0; off >>= 1) {
            acc0[b] += __shfl_down(acc0[b], off, 64);
            acc1[b] += __shfl_down(acc1[b], off, 64);
        }
    }

    __shared__ float sred[4][16];
    int lane = threadIdx.x & 63;
    int wave = threadIdx.x >> 6;
    if (lane == 0) {
#pragma unroll
        for (int b = 0; b < BATCH; ++b) {
            sred[wave][2 * b + 0] = acc0[b];
            sred[wave][2 * b + 1] = acc1[b];
        }
    }
    __syncthreads();
    if (threadIdx.x < 16) {
        float s = sred[0][threadIdx.x] + sred[1][threadIdx.x] +
                  sred[2][threadIdx.x] + sred[3][threadIdx.x];
        partials[blockIdx.x * 16 + threadIdx.x] = s;
    }
}

__global__ __launch_bounds__(256) void final_reduce_kernel(
    const float* __restrict__ partials, float* __restrict__ out)
{
    int j = threadIdx.x & 15;
    int chunk = threadIdx.x >> 4;
    float s = 0.0f;
    int r0 = chunk * (GB / 16);
    for (int r = r0; r < r0 + (GB / 16); ++r)
        s += partials[r * 16 + j];
    __shared__ float tmp[256];
    tmp[threadIdx.x] = s;
    __syncthreads();
    if (threadIdx.x < 16) {
        float t = 0.0f;
#pragma unroll
        for (int c = 0; c < 16; ++c) t += tmp[c * 16 + threadIdx.x];
        out[threadIdx.x] = t;
    }
}

// ---- fallback (round-1 unsorted path) if ws is too small ----
__global__ void zero_out_kernel(float* __restrict__ out) {
    int i = threadIdx.x;
    if (i < 16) out[i] = 0.0f;
}

__global__ __launch_bounds__(256) void interp_grad_kernel(
    const float* __restrict__ imgs, const float* __restrict__ z,
    float* __restrict__ out, int npts)
{
    int p = blockIdx.x * blockDim.x + threadIdx.x;
    float acc0[BATCH];
    float acc1[BATCH];
#pragma unroll
    for (int b = 0; b < BATCH; ++b) { acc0[b] = 0.0f; acc1[b] = 0.0f; }
    if (p < npts) {
        float2 zz = ((const float2*)z)[p];
        float x0y = zz.x * (float)(NYX - 1);
        float x0x = zz.y * (float)(NYX - 1);
        bool oob = (x0y < 0.0f) || (x0y > (float)(NYX - 1)) ||
                   (x0x < 0.0f) || (x0x > (float)(NYX - 1));
        if (!oob) {
            int yg = min((int)floorf(x0y), NYX - 2);
            int xg = min((int)floorf(x0x), NYX - 2);
            float fy = (float)yg - x0y;
            float fx = (float)xg - x0x;
            const float* base = imgs + (size_t)yg * NYX + xg;
#pragma unroll
            for (int b = 0; b < BATCH; ++b) {
#pragma unroll
                for (int c = 0; c < CH; ++c) {
                    const float* pl = base + (size_t)(b * CH + c) * (size_t)NPIX;
                    float g00 = pl[0];
                    float g01 = pl[1];
                    float g10 = pl[NYX];
                    float g11 = pl[NYX + 1];
                    float a1 = g10 - g00;
                    float a2 = g11 - g01;
                    float a3 = g01 - g00;
                    float d  = a1 - a2;
                    acc0[b] += d * fx + a1;
                    acc1[b] += d * fy + a3;
                }
            }
        }
    }
#pragma unroll
    for (int b = 0; b < BATCH; ++b) {
#pragma unroll
        for (int off = 32; off > 0; off >>= 1) {
            acc0[b] += __shfl_down(acc0[b], off, 64);
            acc1[b] += __shfl_down(acc1[b], off, 64);
        }
    }
    __shared__ float sred[4][16];
    int lane = threadIdx.x & 63;
    int wave = threadIdx.x >> 6;
    if (lane == 0) {
#pragma unroll
        for (int b = 0; b < BATCH; ++b) {
            sred[wave][2 * b + 0] = acc0[b];
            sred[wave][2 * b + 1] = acc1[b];
        }
    }
    __syncthreads();
    if (threadIdx.x < 16) {
        float s = sred[0][threadIdx.x] + sred[1][threadIdx.x] +
                  sred[2][threadIdx.x] + sred[3][threadIdx.x];
        atomicAdd(&out[threadIdx.x], s);
    }
}

extern "C" void kernel_launch(void* const* d_in, const int* in_sizes, int n_in,
                              void* d_out, int out_size, void* d_ws, size_t ws_size,
                              hipStream_t stream) {
    const float* imgs = (const float*)d_in[0];
    const float* z    = (const float*)d_in[1];
    float* out        = (float*)d_out;
    int npts = in_sizes[1] / 2;

    size_t ws_need = PART_OFF + (size_t)GB * 16 * sizeof(float);  // ~134.3 MB

    if (ws_size < ws_need) {
        int blocks = (npts + 255) / 256;
        zero_out_kernel<<<1, 64, 0, stream>>>(out);
        interp_grad_kernel<<<blocks, 256, 0, stream>>>(imgs, z, out, npts);
        return;
    }

    float4* T4      = (float4*)d_ws;
    float* partials = (float*)((char*)d_ws + PART_OFF);

    precompute_kernel<<<NYX, 256, 0, stream>>>(imgs, T4);
    gather_kernel<<<GB, 256, 0, stream>>>(z, T4, partials, npts);
    final_reduce_kernel<<<1, 256, 0, stream>>>(partials, out);
}

// Round 9
// 202.475 us; speedup vs baseline: 1.6310x; 1.6310x over previous
//
#include <hip/hip_runtime.h>
#include <hip/hip_fp16.h>

// imgs (8,3,1024,1024) fp32, z (1e6,2) fp32 -> out (8,2) fp32.
// R9: gather-dual of the linear reformulation (R8) with fp16-packed T and
// LDS-staged coalesced writes.
//   gc0(point) = Dy[yg][xg] + u*M[yg][xg],  gc1 = Dx[yg][xg] + v*M[yg][xg]
// with S_b = sum_c imgs[b,c], Dy=S(y+1,x)-S(y,x), Dx=S(y,x+1)-S(y,x),
// M = S(y+1,x+1)-S(y,x+1)-S(y+1,x)+S(y,x).
// T record per pixel: 64 B = uint4[4]: [0]=Dy(8 half), [1]=Dx, [2]=M, [3]=pad.
// One point reads <=48 B from one 128 B line (record 64B-aligned).
// R8 lesson: 128B-stride float4 stores -> 2.3x write amplification (300 MB vs
// 128). Fix: stage records in LDS, copy out as consecutive uint4 per lane.
// fp16 error budget: term err ~1.2e-3, 1M-point random walk -> ~2 abs; thr 58.

#define NYX 1024
#define NPIX (NYX * NYX)
#define BATCH 8
#define CH 3
#define GB 1024                                  // gather blocks
#define PART_OFF ((size_t)NPIX * 64)             // 64 MB of T, then partials

__device__ __forceinline__ unsigned pk2(float a, float b) {
    __half2 h = __floats2half2_rn(a, b);
    return *(unsigned*)&h;
}

__global__ __launch_bounds__(256) void precompute_kernel(
    const float* __restrict__ imgs, uint4* __restrict__ T)
{
    int bid = blockIdx.x;
    int y   = bid >> 2;                  // 0..1023
    int x0  = (bid & 3) << 8;            // 0,256,512,768
    int yp1 = min(y + 1, NYX - 1);       // y=1023 records never read by gather
    int t   = threadIdx.x;

    __shared__ float s0[257];
    __shared__ float s1[257];
    __shared__ uint4 stage[1024];        // 256 records x 64 B = 16 KB

    float Dy[BATCH], Dx[BATCH], Mm[BATCH];

#pragma unroll
    for (int b = 0; b < BATCH; ++b) {
        float a0 = 0.0f, a1 = 0.0f;
#pragma unroll
        for (int c = 0; c < CH; ++c) {
            const float* pl = imgs + (size_t)(b * CH + c) * NPIX;
            a0 += pl[(size_t)y   * NYX + x0 + t];
            a1 += pl[(size_t)yp1 * NYX + x0 + t];
        }
        s0[t] = a0;
        s1[t] = a1;
        if (t == 0) {
            int xe = min(x0 + 256, NYX - 1);   // clamp; x=1023 records unread
            float e0 = 0.0f, e1 = 0.0f;
#pragma unroll
            for (int c = 0; c < CH; ++c) {
                const float* pl = imgs + (size_t)(b * CH + c) * NPIX;
                e0 += pl[(size_t)y   * NYX + xe];
                e1 += pl[(size_t)yp1 * NYX + xe];
            }
            s0[256] = e0;
            s1[256] = e1;
        }
        __syncthreads();
        float c00 = s0[t], c01 = s0[t + 1];
        float c10 = s1[t], c11 = s1[t + 1];
        Dy[b] = c10 - c00;
        Dx[b] = c01 - c00;
        Mm[b] = (c11 - c01) - Dy[b];
        __syncthreads();   // s0/s1 reused next b
    }

    stage[t * 4 + 0] = make_uint4(pk2(Dy[0], Dy[1]), pk2(Dy[2], Dy[3]),
                                  pk2(Dy[4], Dy[5]), pk2(Dy[6], Dy[7]));
    stage[t * 4 + 1] = make_uint4(pk2(Dx[0], Dx[1]), pk2(Dx[2], Dx[3]),
                                  pk2(Dx[4], Dx[5]), pk2(Dx[6], Dx[7]));
    stage[t * 4 + 2] = make_uint4(pk2(Mm[0], Mm[1]), pk2(Mm[2], Mm[3]),
                                  pk2(Mm[4], Mm[5]), pk2(Mm[6], Mm[7]));
    stage[t * 4 + 3] = make_uint4(0u, 0u, 0u, 0u);
    __syncthreads();

    // coalesced copy-out: 1024 consecutive uint4 (16 KB window)
    size_t base4 = ((size_t)y * NYX + x0) * 4;
#pragma unroll
    for (int i = 0; i < 4; ++i)
        T[base4 + i * 256 + t] = stage[i * 256 + t];
}

__global__ __launch_bounds__(256) void gather_kernel(
    const float* __restrict__ z, const uint4* __restrict__ T,
    float* __restrict__ partials, int npts)
{
    float acc0[BATCH];
    float acc1[BATCH];
#pragma unroll
    for (int b = 0; b < BATCH; ++b) { acc0[b] = 0.0f; acc1[b] = 0.0f; }

    int stride = gridDim.x * blockDim.x;
    for (int p = blockIdx.x * blockDim.x + threadIdx.x; p < npts; p += stride) {
        float2 zz = ((const float2*)z)[p];
        float x0y = zz.x * (float)(NYX - 1);
        float x0x = zz.y * (float)(NYX - 1);
        bool oob = (x0y < 0.0f) || (x0y > (float)(NYX - 1)) ||
                   (x0x < 0.0f) || (x0x > (float)(NYX - 1));
        if (oob) continue;
        int yg = min((int)floorf(x0y), NYX - 2);
        int xg = min((int)floorf(x0x), NYX - 2);
        float u = x0x - (float)xg;   // [0,1)
        float v = x0y - (float)yg;
        const uint4* t4 = T + ((size_t)yg * NYX + xg) * 4;
        uint4 qDy = t4[0];
        uint4 qDx = t4[1];
        uint4 qM  = t4[2];
        const __half2* hDy = (const __half2*)&qDy;
        const __half2* hDx = (const __half2*)&qDx;
        const __half2* hM  = (const __half2*)&qM;
#pragma unroll
        for (int j = 0; j < 4; ++j) {
            float2 dy = __half22float2(hDy[j]);
            float2 dx = __half22float2(hDx[j]);
            float2 m  = __half22float2(hM[j]);
            acc0[2 * j + 0] += fmaf(u, m.x, dy.x);
            acc0[2 * j + 1] += fmaf(u, m.y, dy.y);
            acc1[2 * j + 0] += fmaf(v, m.x, dx.x);
            acc1[2 * j + 1] += fmaf(v, m.y, dx.y);
        }
    }

#pragma unroll
    for (int b = 0; b < BATCH; ++b) {
#pragma unroll
        for (int off = 32; off > 0; off >>= 1) {
            acc0[b] += __shfl_down(acc0[b], off, 64);
            acc1[b] += __shfl_down(acc1[b], off, 64);
        }
    }

    __shared__ float sred[4][16];
    int lane = threadIdx.x & 63;
    int wave = threadIdx.x >> 6;
    if (lane == 0) {
#pragma unroll
        for (int b = 0; b < BATCH; ++b) {
            sred[wave][2 * b + 0] = acc0[b];
            sred[wave][2 * b + 1] = acc1[b];
        }
    }
    __syncthreads();
    if (threadIdx.x < 16) {
        float s = sred[0][threadIdx.x] + sred[1][threadIdx.x] +
                  sred[2][threadIdx.x] + sred[3][threadIdx.x];
        partials[blockIdx.x * 16 + threadIdx.x] = s;
    }
}

__global__ __launch_bounds__(256) void final_reduce_kernel(
    const float* __restrict__ partials, float* __restrict__ out)
{
    int j = threadIdx.x & 15;
    int chunk = threadIdx.x >> 4;
    float s = 0.0f;
    int r0 = chunk * (GB / 16);
    for (int r = r0; r < r0 + (GB / 16); ++r)
        s += partials[r * 16 + j];
    __shared__ float tmp[256];
    tmp[threadIdx.x] = s;
    __syncthreads();
    if (threadIdx.x < 16) {
        float t = 0.0f;
#pragma unroll
        for (int c = 0; c < 16; ++c) t += tmp[c * 16 + threadIdx.x];
        out[threadIdx.x] = t;
    }
}

// ---- fallback (round-1 unsorted path) if ws is too small ----
__global__ void zero_out_kernel(float* __restrict__ out) {
    int i = threadIdx.x;
    if (i < 16) out[i] = 0.0f;
}

__global__ __launch_bounds__(256) void interp_grad_kernel(
    const float* __restrict__ imgs, const float* __restrict__ z,
    float* __restrict__ out, int npts)
{
    int p = blockIdx.x * blockDim.x + threadIdx.x;
    float acc0[BATCH];
    float acc1[BATCH];
#pragma unroll
    for (int b = 0; b < BATCH; ++b) { acc0[b] = 0.0f; acc1[b] = 0.0f; }
    if (p < npts) {
        float2 zz = ((const float2*)z)[p];
        float x0y = zz.x * (float)(NYX - 1);
        float x0x = zz.y * (float)(NYX - 1);
        bool oob = (x0y < 0.0f) || (x0y > (float)(NYX - 1)) ||
                   (x0x < 0.0f) || (x0x > (float)(NYX - 1));
        if (!oob) {
            int yg = min((int)floorf(x0y), NYX - 2);
            int xg = min((int)floorf(x0x), NYX - 2);
            float fy = (float)yg - x0y;
            float fx = (float)xg - x0x;
            const float* base = imgs + (size_t)yg * NYX + xg;
#pragma unroll
            for (int b = 0; b < BATCH; ++b) {
#pragma unroll
                for (int c = 0; c < CH; ++c) {
                    const float* pl = base + (size_t)(b * CH + c) * (size_t)NPIX;
                    float g00 = pl[0];
                    float g01 = pl[1];
                    float g10 = pl[NYX];
                    float g11 = pl[NYX + 1];
                    float a1 = g10 - g00;
                    float a2 = g11 - g01;
                    float a3 = g01 - g00;
                    float d  = a1 - a2;
                    acc0[b] += d * fx + a1;
                    acc1[b] += d * fy + a3;
                }
            }
        }
    }
#pragma unroll
    for (int b = 0; b < BATCH; ++b) {
#pragma unroll
        for (int off = 32; off > 0; off >>= 1) {
            acc0[b] += __shfl_down(acc0[b], off, 64);
            acc1[b] += __shfl_down(acc1[b], off, 64);
        }
    }
    __shared__ float sred[4][16];
    int lane = threadIdx.x & 63;
    int wave = threadIdx.x >> 6;
    if (lane == 0) {
#pragma unroll
        for (int b = 0; b < BATCH; ++b) {
            sred[wave][2 * b + 0] = acc0[b];
            sred[wave][2 * b + 1] = acc1[b];
        }
    }
    __syncthreads();
    if (threadIdx.x < 16) {
        float s = sred[0][threadIdx.x] + sred[1][threadIdx.x] +
                  sred[2][threadIdx.x] + sred[3][threadIdx.x];
        atomicAdd(&out[threadIdx.x], s);
    }
}

extern "C" void kernel_launch(void* const* d_in, const int* in_sizes, int n_in,
                              void* d_out, int out_size, void* d_ws, size_t ws_size,
                              hipStream_t stream) {
    const float* imgs = (const float*)d_in[0];
    const float* z    = (const float*)d_in[1];
    float* out        = (float*)d_out;
    int npts = in_sizes[1] / 2;

    size_t ws_need = PART_OFF + (size_t)GB * 16 * sizeof(float);  // ~64.1 MB

    if (ws_size < ws_need) {
        int blocks = (npts + 255) / 256;
        zero_out_kernel<<<1, 64, 0, stream>>>(out);
        interp_grad_kernel<<<blocks, 256, 0, stream>>>(imgs, z, out, npts);
        return;
    }

    uint4* T        = (uint4*)d_ws;
    float* partials = (float*)((char*)d_ws + PART_OFF);

    precompute_kernel<<<NYX * 4, 256, 0, stream>>>(imgs, T);
    gather_kernel<<<GB, 256, 0, stream>>>(z, T, partials, npts);
    final_reduce_kernel<<<1, 256, 0, stream>>>(partials, out);
}